// Round 16
// baseline (111.083 us; speedup 1.0000x reference)
//
#include <hip/hip_runtime.h>
#include <hip/hip_bf16.h>
#include <math.h>

// PLANAttention, bf16/MFMA pipeline (round 16: k_proj rebuilt with NO LDS and
// NO barriers — each wave computes an independent 64x64 tile, A direct from
// fp32 feat (cvt in reg), B direct from bf16 Wb (both L2-resident). Values and
// accumulation order bit-identical to rounds 11/15):
//  1) k_cvt_w: 8 weight mats fp32 -> bf16 (Wb)
//  2) k_proj: fused QKV proj (top+bot merged) -> pixel-major bf16 K/Q/V
//  3) k_attn: per (pixel,head) wave: S=Q.K^T (1 mfma), O=S.V (2 mfma)
//  4) k_fold: pat -> botRet bf16 (gather <=4 windows, no atomics)
//  5) k_fuse: fuse-top + fuse-bot merged -> fp32 d_out

typedef __attribute__((ext_vector_type(8))) short  bh8;
typedef __attribute__((ext_vector_type(4))) short  bh4;
typedef __attribute__((ext_vector_type(4))) float  f32x4;
typedef unsigned short u16;

static __device__ __forceinline__ u16 f2b(float x) {
    __hip_bfloat16 h = __float2bfloat16(x);
    return __builtin_bit_cast(u16, h);
}
static __device__ __forceinline__ float b2f(u16 u) {
    unsigned v = ((unsigned)u) << 16;
    return __builtin_bit_cast(float, v);
}

// async global->LDS, 16B per lane (k_fuse only).
static __device__ __forceinline__ void gload16(const u16* g, u16* l) {
    __builtin_amdgcn_global_load_lds(
        (const __attribute__((address_space(1))) unsigned int*)g,
        (__attribute__((address_space(3))) unsigned int*)l, 16, 0, 0);
}

// ---------------- weight convert: 8 x 256x256 fp32 -> bf16 ----------------
__global__ __launch_bounds__(256) void k_cvt_w(
    const float* w0, const float* w1, const float* w2, const float* w3,
    const float* w4, const float* w5, const float* w6, const float* w7,
    u16* __restrict__ Wb)
{
    const float* srcs[8] = {w0,w1,w2,w3,w4,w5,w6,w7};
    const float* src = srcs[blockIdx.y];
    int i = (blockIdx.x * 256 + threadIdx.x) * 4;
    float4 v = *(const float4*)&src[i];
    u16 tmp[4] = { f2b(v.x), f2b(v.y), f2b(v.z), f2b(v.w) };
    *(uint2*)&Wb[(size_t)blockIdx.y * 65536 + i] = *(uint2*)tmp;
}

// ---------------- proj (top + bot merged), NO LDS / NO barriers ----------------
// grid 1920 linear (8*240), XCD-swizzled: each XCD gets 80 consecutive y-tiles
// x all 3 n-tiles (A-tile reuse within one L2). BM=64, BN=256, 4 waves; each
// wave owns a 64x64 output tile (wn = wave id), fully independent.
// A[m=pix][k=c]: lane (l16,grp), mi: 8 stride-S fp32 loads (64B per 16-lane
// segment, L2-hot after first wave) -> f2b -> bh8. Values identical to the
// old LDS path. B[n][k]: 16B bh8 loads from Wb (L2-resident weights).
// K order kt=0..7 identical -> bit-identical accumulation vs rounds 8-15.
__global__ __launch_bounds__(256) void k_proj(
    const float* __restrict__ top_feat, const float* __restrict__ bot_feat,
    const u16* __restrict__ Wb,
    u16* __restrict__ tK, u16* __restrict__ bK, size_t TOPU, size_t BOTU)
{
    const int lbid  = (blockIdx.x & 7) * 240 + (blockIdx.x >> 3);  // bijective, 1920=8*240
    const int yb    = lbid / 3;
    const int n0    = (lbid - yb * 3) * 256;
    const bool istop = yb < 128;
    const float* feat = istop ? top_feat : bot_feat;
    const u16* Bw   = istop ? Wb : (Wb + 3 * 65536);
    u16* Yp         = istop ? tK : bK;
    const size_t arrsz = istop ? TOPU : BOTU;
    const int S     = istop ? 4096 : 16384;
    const int m0g   = (istop ? yb : (yb - 128)) * 64;
    const int b     = istop ? (m0g >> 12) : (m0g >> 14);
    const int pix0  = m0g & (S - 1);
    const int t  = threadIdx.x;
    const int w  = t >> 6, wl = t & 63, l16 = wl & 15, grp = wl >> 4;

    // lane bases
    const float* Xl = feat + (size_t)b * 256 * S + pix0 + l16;  // + c*S + mi*16
    const u16*   Bl = Bw + (size_t)(n0 + w * 64 + l16) * 256 + grp * 8;

    f32x4 acc[4][4];
    #pragma unroll
    for (int i = 0; i < 4; ++i)
        #pragma unroll
        for (int j = 0; j < 4; ++j) acc[i][j] = (f32x4){0.f, 0.f, 0.f, 0.f};

    for (int kt = 0; kt < 8; ++kt) {      // not unrolled: avoid prefetch spill
        const size_t kc = (size_t)(kt * 32 + grp * 8) * S;
        bh8 bf[4];
        #pragma unroll
        for (int ni = 0; ni < 4; ++ni)
            bf[ni] = *(const bh8*)(Bl + (size_t)ni * 16 * 256 + kt * 32);
        bh8 af[4];
        #pragma unroll
        for (int mi = 0; mi < 4; ++mi) {
            bh8 a;
            #pragma unroll
            for (int e = 0; e < 8; ++e)
                a[e] = (short)f2b(Xl[kc + (size_t)e * S + mi * 16]);
            af[mi] = a;
        }
        #pragma unroll
        for (int mi = 0; mi < 4; ++mi)
            #pragma unroll
            for (int ni = 0; ni < 4; ++ni)
                acc[mi][ni] = __builtin_amdgcn_mfma_f32_16x16x32_bf16(
                    af[mi], bf[ni], acc[mi][ni], 0, 0, 0);
    }

    #pragma unroll
    for (int mi = 0; mi < 4; ++mi)
        #pragma unroll
        for (int ni = 0; ni < 4; ++ni)
            #pragma unroll
            for (int r = 0; r < 4; ++r) {
                int m = m0g + mi*16 + grp*4 + r;
                int n = n0 + w*64 + ni*16 + l16;
                Yp[(size_t)(n >> 8) * arrsz + (size_t)m * 256 + (n & 255)]
                    = f2b(acc[mi][ni][r]);
            }
}

// Shared GEMM staging/compute for k_fuse (round-3 verified): C[m][n]=sum_k A[m][k]*B[n][k].
#define GEMM_STAGE(bufi, kk) do {                                             \
        _Pragma("unroll")                                                     \
        for (int it = 0; it < 2; ++it) {                                      \
            int lin = it * 256 + t;                                           \
            int row = lin >> 3, c = lin & 7;                                  \
            int cs = c ^ (row & 7);                                           \
            gload16(&A[(size_t)(m0 + row) * 256 + (kk) + cs * 8],             \
                    &AT[bufi][lin * 8]);                                      \
        }                                                                     \
        _Pragma("unroll")                                                     \
        for (int it = 0; it < 8; ++it) {                                      \
            int lin = it * 256 + t;                                           \
            int row = lin >> 3, c = lin & 7;                                  \
            int cs = c ^ (row & 7);                                           \
            gload16(&B[(size_t)(n0 + row) * 256 + (kk) + cs * 8],             \
                    &BT[bufi][lin * 8]);                                      \
        }                                                                     \
    } while (0)

#define GEMM_MAIN()                                                           \
    GEMM_STAGE(0, 0);                                                         \
    int cur = 0;                                                              \
    for (int kt = 0; kt < 4; ++kt) {                                          \
        __syncthreads();                                                      \
        if (kt < 3) GEMM_STAGE(cur ^ 1, (kt + 1) * 64);                       \
        _Pragma("unroll")                                                     \
        for (int ks = 0; ks < 2; ++ks) {                                      \
            bh8 af[4], bf[4];                                                 \
            _Pragma("unroll")                                                 \
            for (int mi = 0; mi < 4; ++mi) {                                  \
                int row = mi * 16 + l16;                                      \
                int pc = (ks * 4 + grp) ^ (row & 7);                          \
                af[mi] = *(const bh8*)&AT[cur][row * 64 + pc * 8];            \
            }                                                                 \
            _Pragma("unroll")                                                 \
            for (int ni = 0; ni < 4; ++ni) {                                  \
                int row = w * 64 + ni * 16 + l16;                             \
                int pc = (ks * 4 + grp) ^ (row & 7);                          \
                bf[ni] = *(const bh8*)&BT[cur][row * 64 + pc * 8];            \
            }                                                                 \
            _Pragma("unroll")                                                 \
            for (int mi = 0; mi < 4; ++mi)                                    \
                _Pragma("unroll")                                             \
                for (int ni = 0; ni < 4; ++ni)                                \
                    acc[mi][ni] = __builtin_amdgcn_mfma_f32_16x16x32_bf16(    \
                        af[mi], bf[ni], acc[mi][ni], 0, 0, 0);                \
        }                                                                     \
        cur ^= 1;                                                             \
    }

// ---------------- fuse (top + bot merged): C[m=o][n=pixrow] -> fp32 ----------------
// blocks [0,128): top (lgS=12, n-tiles 32, m-tiles 4); [128,640): bot (lgS=14, 128x4)
// B-tile sharers are bid strides 32 / 128 (== 0 mod 8) -> already same-XCD.
__global__ __launch_bounds__(256) void k_fuse(
    const u16* __restrict__ Wb, const u16* __restrict__ tRet,
    const u16* __restrict__ botRet, float* __restrict__ top_out,
    float* __restrict__ bot_out)
{
    const int bid = blockIdx.x;
    const u16* A; const u16* B; float* Yf; int lgS, n0, m0;
    if (bid < 128) {
        A = Wb + 6 * 65536; B = tRet; Yf = top_out; lgS = 12;
        n0 = (bid & 31) * 256; m0 = (bid >> 5) * 64;
    } else {
        int i = bid - 128;
        A = Wb + 7 * 65536; B = botRet; Yf = bot_out; lgS = 14;
        n0 = (i & 127) * 256; m0 = (i >> 7) * 64;
    }
    const int t  = threadIdx.x;
    const int w  = t >> 6, wl = t & 63, l16 = wl & 15, grp = wl >> 4;

    __shared__ __align__(16) u16 AT[2][64 * 64];
    __shared__ __align__(16) u16 BT[2][256 * 64];

    f32x4 acc[4][4];
    #pragma unroll
    for (int i = 0; i < 4; ++i)
        #pragma unroll
        for (int j = 0; j < 4; ++j) acc[i][j] = (f32x4){0.f, 0.f, 0.f, 0.f};

    GEMM_MAIN();

    #pragma unroll
    for (int mi = 0; mi < 4; ++mi)
        #pragma unroll
        for (int ni = 0; ni < 4; ++ni)
            #pragma unroll
            for (int r = 0; r < 4; ++r) {
                int m = m0 + mi*16 + grp*4 + r;
                int n = n0 + w*64 + ni*16 + l16;
                int bb = n >> lgS, s = n & ((1 << lgS) - 1);
                Yf[(((size_t)bb * 256 + m) << lgS) + s] = acc[mi][ni][r];
            }
}

// ---------------- attention: one wave per (pixel, head-pair) ----------------
// grid 8192 linear, XCD-swizzled: each XCD owns a contiguous 1024-pixel band
// (16 image rows) -> bot-neighbor lines (2.25x amplified) reuse one L2.
__global__ __launch_bounds__(256) void k_attn(
    const u16* __restrict__ tK, const u16* __restrict__ tQ, const u16* __restrict__ tV,
    const u16* __restrict__ bK, const u16* __restrict__ bQ, const u16* __restrict__ bV,
    u16* __restrict__ tRet, u16* __restrict__ pat)
{
    const int lbid = (blockIdx.x & 7) * 1024 + (blockIdx.x >> 3);  // 8192 = 8*1024
    const int pix = lbid & 4095;    // 0..4095
    const int b   = lbid >> 12;
    const int w   = threadIdx.x >> 6;
    const int wl  = threadIdx.x & 63;
    const int l16 = wl & 15, grp = wl >> 4;
    const int y = pix >> 6, x = pix & 63;

    __shared__ u16 Ssm[4][16][24];        // [wave][q][kpos], stride 48B
    __shared__ __align__(16) u16 Vsm[4][2][16][16]; // [wave][v-half][kpos][v16]

    // position p = l16: p=0 top pixel, p=1..9 bot neighbor, p>=10 pad
    const int p = l16;
    bool pvalid = false; int bpix = 0; const bool istop = (p == 0);
    if (p == 0) pvalid = true;
    else if (p < 10) {
        int pm = p - 1; int i = (pm * 11) >> 5; int j = pm - 3 * i;
        int by = 2 * y + i - 1, bx = 2 * x + j - 1;
        pvalid = ((unsigned)by < 128u) && ((unsigned)bx < 128u);
        bpix = by * 128 + bx;
    }
    const size_t topRow = ((size_t)b * 4096  + pix)  * 256;
    const size_t botRow = ((size_t)b * 16384 + bpix) * 256;
    const float scale = 0.17677669529663687f; // 1/sqrt(32)

    #pragma unroll
    for (int hi = 0; hi < 2; ++hi) {
        const int h = w + hi * 4;
        const size_t off = (istop ? topRow : botRow) + h * 32 + grp * 8;
        bh8 aQ = {}, aK = {}, vV = {};
        if (pvalid) {
            if (istop) {
                aQ = *(const bh8*)(tQ + off);
                aK = *(const bh8*)(tK + off);
                vV = *(const bh8*)(tV + off);
            } else {
                aQ = *(const bh8*)(bQ + off);
                aK = *(const bh8*)(bK + off);
                vV = *(const bh8*)(bV + off);
            }
        }
        // stage V rows (zeros for invalid rows): half = grp>>1, chunk (grp&1)*8
        *(bh8*)&Vsm[w][grp >> 1][p][(grp & 1) * 8] = vV;

        // S = Q.K^T   (A rows = query pos, B cols = key pos, k = d contiguous)
        f32x4 z = {0.f, 0.f, 0.f, 0.f};
        f32x4 sC = __builtin_amdgcn_mfma_f32_16x16x32_bf16(aQ, aK, z, 0, 0, 0);
        #pragma unroll
        for (int r = 0; r < 4; ++r)
            Ssm[w][grp * 4 + r][l16] = f2b(sC[r] * scale);

        // A_S: row q=l16, k-slots (grp,i<4) = kpos 4*grp+i ; slots i>=4 zero
        bh8 aS = {};
        *(bh4*)&aS = *(const bh4*)&Ssm[w][l16][grp * 4];

        // B_V: slot (grp,i<4) = V[kpos=4*grp+i][v], consistent with A_S labeling
        bh8 bv0 = {}, bv1 = {};
        #pragma unroll
        for (int j = 0; j < 4; ++j) {
            bv0[j] = (short)Vsm[w][0][grp * 4 + j][l16];
            bv1[j] = (short)Vsm[w][1][grp * 4 + j][l16];
        }
        f32x4 oc0 = __builtin_amdgcn_mfma_f32_16x16x32_bf16(aS, bv0, z, 0, 0, 0);
        f32x4 oc1 = __builtin_amdgcn_mfma_f32_16x16x32_bf16(aS, bv1, z, 0, 0, 0);

        // outputs: row q = grp*4+r, col v = l16 (+16 for oc1)
        if (grp == 0) {
            size_t o = topRow + (size_t)h * 32;
            tRet[o + l16]      = f2b(oc0[0]);
            tRet[o + 16 + l16] = f2b(oc1[0]);
        }
        #pragma unroll
        for (int r = 0; r < 4; ++r) {
            int q = grp * 4 + r;
            if (q >= 1 && q <= 9) {
                size_t base = ((((size_t)b * 8 + h) * 9 + (q - 1)) * 4096 + pix) * 32;
                pat[base + l16]      = f2b(oc0[r]);
                pat[base + 16 + l16] = f2b(oc1[r]);
            }
        }
    }
}

// ---------------- fold: pat [b][h][9][4096][32] -> botRet (B,16384,256) bf16 ----------------
// grid 4096, XCD-swizzled: contiguous bpix bands per XCD for pat-line reuse.
__global__ __launch_bounds__(256) void k_fold(
    const u16* __restrict__ pat, u16* __restrict__ botRet)
{
    const int lbid = (blockIdx.x & 7) * 512 + (blockIdx.x >> 3);   // 4096 = 8*512
    int tid = lbid * 256 + threadIdx.x;             // 1,048,576 threads
    int vchunk = tid & 3;                           // 8 v's each
    int ri = tid >> 2;                              // (b*16384 + bpix)*8 + h
    int b = ri >> 17;
    int bpix = (ri >> 3) & 16383;
    int h = ri & 7;
    int by = bpix >> 7, bx = bpix & 127;
    int v0 = vchunk * 8;

    float acc[8];
    #pragma unroll
    for (int e = 0; e < 8; ++e) acc[e] = 0.f;

    for (int iy = 0; iy < 3; ++iy) {
        int ty = by + 1 - iy;
        if (ty & 1) continue;
        int yy = ty >> 1;
        if ((unsigned)yy >= 64u) continue;
        for (int jx = 0; jx < 3; ++jx) {
            int tx = bx + 1 - jx;
            if (tx & 1) continue;
            int xx = tx >> 1;
            if ((unsigned)xx >= 64u) continue;
            int q = iy * 3 + jx;
            size_t addr = ((((size_t)b * 8 + h) * 9 + q) * 4096 + (yy * 64 + xx)) * 32 + v0;
            uint4 pv = *(const uint4*)&pat[addr];
            const u16* pp = (const u16*)&pv;
            #pragma unroll
            for (int e = 0; e < 8; ++e) acc[e] += b2f(pp[e]);
        }
    }
    u16 tmp[8];
    #pragma unroll
    for (int e = 0; e < 8; ++e) tmp[e] = f2b(acc[e]);
    *(uint4*)&botRet[((size_t)b * 16384 + bpix) * 256 + h * 32 + v0] = *(uint4*)tmp;
}

extern "C" void kernel_launch(void* const* d_in, const int* in_sizes, int n_in,
                              void* d_out, int out_size, void* d_ws, size_t ws_size,
                              hipStream_t stream) {
    const float* top_feat = (const float*)d_in[0];
    const float* bot_feat = (const float*)d_in[1];

    float* out     = (float*)d_out;
    float* top_out = out;                            // (2,256,64,64)
    float* bot_out = out + (size_t)2 * 256 * 4096;   // (2,256,128,128)

    const size_t TOPU = (size_t)2 * 4096  * 256;   // ushort counts
    const size_t BOTU = (size_t)2 * 16384 * 256;
    char* p = (char*)d_ws;
    u16* Wb     = (u16*)p;  p += (size_t)8 * 65536 * 2;   // 1.0 MB
    u16* tK     = (u16*)p;  p += TOPU * 2;
    u16* tQ     = (u16*)p;  p += TOPU * 2;
    u16* tV     = (u16*)p;  p += TOPU * 2;                // 12.6 MB
    u16* bK     = (u16*)p;  p += BOTU * 2;
    u16* bQ     = (u16*)p;  p += BOTU * 2;
    u16* bV     = (u16*)p;  p += BOTU * 2;                // 50.3 MB
    u16* tRet   = (u16*)p;  p += TOPU * 2;                // 4.2 MB
    u16* pat    = (u16*)p;  p += (size_t)2*8*9*4096*32*2; // 37.7 MB
    u16* botRet = (u16*)p;  p += BOTU * 2;                // 16.8 MB

    // weights -> bf16 (order: tK,tQ,tV,bK,bQ,bV,tFuse,bFuse)
    k_cvt_w<<<dim3(64, 8), dim3(256), 0, stream>>>(
        (const float*)d_in[2], (const float*)d_in[3], (const float*)d_in[4],
        (const float*)d_in[5], (const float*)d_in[6], (const float*)d_in[7],
        (const float*)d_in[8], (const float*)d_in[9], Wb);

    // fused QKV projections, top+bot merged, no-LDS wave-independent, XCD-swizzled
    k_proj<<<dim3(1920), dim3(256), 0, stream>>>(top_feat, bot_feat, Wb,
                                                 tK, bK, TOPU, BOTU);

    // attention (XCD-swizzled pixel bands)
    k_attn<<<dim3(8192), dim3(256), 0, stream>>>(tK, tQ, tV, bK, bQ, bV, tRet, pat);

    // fold bot windows (XCD-swizzled)
    k_fold<<<dim3(4096), dim3(256), 0, stream>>>(pat, botRet);

    // fuse GEMMs, top+bot merged -> fp32 channel-major outputs
    k_fuse<<<dim3(640), dim3(256), 0, stream>>>(Wb, tRet, botRet, top_out, bot_out);
}

// Round 17
// 103.215 us; speedup vs baseline: 1.0762x; 1.0762x over previous
//
#include <hip/hip_runtime.h>
#include <hip/hip_bf16.h>
#include <math.h>

// PLANAttention, bf16/MFMA pipeline (round 17: k_proj = stage-A-once (64 KB,
// one barrier) + zero-sync main loop with B direct from L2-resident weights.
// r8-r15's bottleneck was the per-K-step barrier chain; r16 showed A needs LDS
// broadcast. This keeps both fixes. Values bit-identical to rounds 11/15):
//  1) k_cvt_w: 8 weight mats fp32 -> bf16 (Wb)
//  2) k_proj: fused QKV proj (top+bot merged) -> pixel-major bf16 K/Q/V
//  3) k_attn: per (pixel,head) wave: S=Q.K^T (1 mfma), O=S.V (2 mfma)
//  4) k_fold: pat -> botRet bf16 (gather <=4 windows, no atomics)
//  5) k_fuse: fuse-top + fuse-bot merged -> fp32 d_out

typedef __attribute__((ext_vector_type(8))) short  bh8;
typedef __attribute__((ext_vector_type(4))) short  bh4;
typedef __attribute__((ext_vector_type(4))) float  f32x4;
typedef unsigned short u16;

static __device__ __forceinline__ u16 f2b(float x) {
    __hip_bfloat16 h = __float2bfloat16(x);
    return __builtin_bit_cast(u16, h);
}
static __device__ __forceinline__ float b2f(u16 u) {
    unsigned v = ((unsigned)u) << 16;
    return __builtin_bit_cast(float, v);
}

// async global->LDS, 16B per lane (k_fuse only).
static __device__ __forceinline__ void gload16(const u16* g, u16* l) {
    __builtin_amdgcn_global_load_lds(
        (const __attribute__((address_space(1))) unsigned int*)g,
        (__attribute__((address_space(3))) unsigned int*)l, 16, 0, 0);
}

// ---------------- weight convert: 8 x 256x256 fp32 -> bf16 ----------------
__global__ __launch_bounds__(256) void k_cvt_w(
    const float* w0, const float* w1, const float* w2, const float* w3,
    const float* w4, const float* w5, const float* w6, const float* w7,
    u16* __restrict__ Wb)
{
    const float* srcs[8] = {w0,w1,w2,w3,w4,w5,w6,w7};
    const float* src = srcs[blockIdx.y];
    int i = (blockIdx.x * 256 + threadIdx.x) * 4;
    float4 v = *(const float4*)&src[i];
    u16 tmp[4] = { f2b(v.x), f2b(v.y), f2b(v.z), f2b(v.w) };
    *(uint2*)&Wb[(size_t)blockIdx.y * 65536 + i] = *(uint2*)tmp;
}

// ---------------- proj: stage-A-once + zero-sync main loop ----------------
// grid 960 XCD-swizzled (each XCD: 40 y-tiles x 3 n-tiles). BM=128, BN=256,
// 512 thr, 8 waves (wm = w>>2 M-half, wn = w&3 N-quarter), per-wave 64x64 out.
// Prologue: full A-tile [128 pix][256 c] fp32 -> bf16 -> 64 KB LDS, chunks
// (16B = 8 c) at slot = chunk ^ (apix & 31) (involution, both sides). ONE
// barrier. Main loop kt=0..7: af = ds_read_b128 (conflict-free), bf = 16B
// direct loads from L2-resident Wb, 16 MFMA. No barriers -> waves free-run.
// c-layout: chunk slab*4+oct holds c = slab*32+oct*8+e -> fragment reads give
// exactly r11's operand values in the same kt order: bit-identical output.
__global__ __launch_bounds__(512) void k_proj(
    const float* __restrict__ top_feat, const float* __restrict__ bot_feat,
    const u16* __restrict__ Wb,
    u16* __restrict__ tK, u16* __restrict__ bK, size_t TOPU, size_t BOTU)
{
    const int lbid  = (blockIdx.x & 7) * 120 + (blockIdx.x >> 3);  // bijective, 960=8*120
    const int yb    = lbid / 3;
    const int n0    = (lbid - yb * 3) * 256;
    const bool istop = yb < 64;
    const float* feat = istop ? top_feat : bot_feat;
    const u16* Bw   = istop ? Wb : (Wb + 3 * 65536);
    u16* Yp         = istop ? tK : bK;
    const size_t arrsz = istop ? TOPU : BOTU;
    const int S     = istop ? 4096 : 16384;
    const int m0g   = (istop ? yb : (yb - 64)) * 128;
    const int b     = istop ? (m0g >> 12) : (m0g >> 14);
    const int pix0  = m0g & (S - 1);
    const float* Xb = feat + (size_t)b * 256 * S;
    const int t  = threadIdx.x;
    const int w  = t >> 6, wl = t & 63, l16 = wl & 15, grp = wl >> 4;
    const int wm = w >> 2, wn = w & 3;
    const int apix = t & 127;            // lane's pixel for A staging
    const int oct  = t >> 7;             // c-octet within a 32-c slab (0..3)

    __shared__ __align__(16) u16 AT[128 * 256];   // 64 KB, row=pixel, 32 chunks

    float a0[8], a1[8];   // phase-local, statically indexed only

#define LOADA(R, slab) do {                                                   \
        _Pragma("unroll")                                                     \
        for (int e = 0; e < 8; ++e)                                           \
            R[e] = Xb[(size_t)((slab) * 32 + oct * 8 + e) * S + pix0 + apix]; \
    } while (0)

#define WRITEA(R, slab) do {                                                  \
        u16 tmp[8];                                                           \
        _Pragma("unroll")                                                     \
        for (int e = 0; e < 8; ++e) tmp[e] = f2b(R[e]);                       \
        int chunk = (slab) * 4 + oct;                                         \
        int slot  = chunk ^ (apix & 31);                                      \
        *(uint4*)&AT[apix * 256 + slot * 8] = *(uint4*)tmp;                   \
    } while (0)

    LOADA(a0, 0);  LOADA(a1, 1);
    WRITEA(a0, 0); LOADA(a0, 2);
    WRITEA(a1, 1); LOADA(a1, 3);
    WRITEA(a0, 2); LOADA(a0, 4);
    WRITEA(a1, 3); LOADA(a1, 5);
    WRITEA(a0, 4); LOADA(a0, 6);
    WRITEA(a1, 5); LOADA(a1, 7);
    WRITEA(a0, 6);
    WRITEA(a1, 7);
#undef LOADA
#undef WRITEA
    __syncthreads();   // the ONLY barrier in this kernel

    // per-lane B fragment base: row = n0 + wn*64 + ni*16 + l16, k = kt*32+grp*8
    const u16* Bl = Bw + (size_t)(n0 + wn * 64 + l16) * 256 + grp * 8;

    f32x4 acc[4][4];
    #pragma unroll
    for (int i = 0; i < 4; ++i)
        #pragma unroll
        for (int j = 0; j < 4; ++j) acc[i][j] = (f32x4){0.f, 0.f, 0.f, 0.f};

    #pragma unroll 2
    for (int kt = 0; kt < 8; ++kt) {
        bh8 bf[4];
        #pragma unroll
        for (int ni = 0; ni < 4; ++ni)
            bf[ni] = *(const bh8*)(Bl + (size_t)ni * 16 * 256 + kt * 32);
        bh8 af[4];
        #pragma unroll
        for (int mi = 0; mi < 4; ++mi) {
            int row = wm * 64 + mi * 16 + l16;
            int chunk = kt * 4 + grp;
            int slot  = chunk ^ (row & 31);
            af[mi] = *(const bh8*)&AT[row * 256 + slot * 8];
        }
        #pragma unroll
        for (int mi = 0; mi < 4; ++mi)
            #pragma unroll
            for (int ni = 0; ni < 4; ++ni)
                acc[mi][ni] = __builtin_amdgcn_mfma_f32_16x16x32_bf16(
                    af[mi], bf[ni], acc[mi][ni], 0, 0, 0);
    }

    #pragma unroll
    for (int mi = 0; mi < 4; ++mi)
        #pragma unroll
        for (int ni = 0; ni < 4; ++ni)
            #pragma unroll
            for (int r = 0; r < 4; ++r) {
                int m = m0g + wm*64 + mi*16 + grp*4 + r;
                int n = n0 + wn*64 + ni*16 + l16;
                Yp[(size_t)(n >> 8) * arrsz + (size_t)m * 256 + (n & 255)]
                    = f2b(acc[mi][ni][r]);
            }
}

// Shared GEMM staging/compute for k_fuse (round-3 verified): C[m][n]=sum_k A[m][k]*B[n][k].
#define GEMM_STAGE(bufi, kk) do {                                             \
        _Pragma("unroll")                                                     \
        for (int it = 0; it < 2; ++it) {                                      \
            int lin = it * 256 + t;                                           \
            int row = lin >> 3, c = lin & 7;                                  \
            int cs = c ^ (row & 7);                                           \
            gload16(&A[(size_t)(m0 + row) * 256 + (kk) + cs * 8],             \
                    &AT[bufi][lin * 8]);                                      \
        }                                                                     \
        _Pragma("unroll")                                                     \
        for (int it = 0; it < 8; ++it) {                                      \
            int lin = it * 256 + t;                                           \
            int row = lin >> 3, c = lin & 7;                                  \
            int cs = c ^ (row & 7);                                           \
            gload16(&B[(size_t)(n0 + row) * 256 + (kk) + cs * 8],             \
                    &BT[bufi][lin * 8]);                                      \
        }                                                                     \
    } while (0)

#define GEMM_MAIN()                                                           \
    GEMM_STAGE(0, 0);                                                         \
    int cur = 0;                                                              \
    for (int kt = 0; kt < 4; ++kt) {                                          \
        __syncthreads();                                                      \
        if (kt < 3) GEMM_STAGE(cur ^ 1, (kt + 1) * 64);                       \
        _Pragma("unroll")                                                     \
        for (int ks = 0; ks < 2; ++ks) {                                      \
            bh8 af[4], bf[4];                                                 \
            _Pragma("unroll")                                                 \
            for (int mi = 0; mi < 4; ++mi) {                                  \
                int row = mi * 16 + l16;                                      \
                int pc = (ks * 4 + grp) ^ (row & 7);                          \
                af[mi] = *(const bh8*)&AT[cur][row * 64 + pc * 8];            \
            }                                                                 \
            _Pragma("unroll")                                                 \
            for (int ni = 0; ni < 4; ++ni) {                                  \
                int row = w * 64 + ni * 16 + l16;                             \
                int pc = (ks * 4 + grp) ^ (row & 7);                          \
                bf[ni] = *(const bh8*)&BT[cur][row * 64 + pc * 8];            \
            }                                                                 \
            _Pragma("unroll")                                                 \
            for (int mi = 0; mi < 4; ++mi)                                    \
                _Pragma("unroll")                                             \
                for (int ni = 0; ni < 4; ++ni)                                \
                    acc[mi][ni] = __builtin_amdgcn_mfma_f32_16x16x32_bf16(    \
                        af[mi], bf[ni], acc[mi][ni], 0, 0, 0);                \
        }                                                                     \
        cur ^= 1;                                                             \
    }

// ---------------- fuse (top + bot merged): C[m=o][n=pixrow] -> fp32 ----------------
__global__ __launch_bounds__(256) void k_fuse(
    const u16* __restrict__ Wb, const u16* __restrict__ tRet,
    const u16* __restrict__ botRet, float* __restrict__ top_out,
    float* __restrict__ bot_out)
{
    const int bid = blockIdx.x;
    const u16* A; const u16* B; float* Yf; int lgS, n0, m0;
    if (bid < 128) {
        A = Wb + 6 * 65536; B = tRet; Yf = top_out; lgS = 12;
        n0 = (bid & 31) * 256; m0 = (bid >> 5) * 64;
    } else {
        int i = bid - 128;
        A = Wb + 7 * 65536; B = botRet; Yf = bot_out; lgS = 14;
        n0 = (i & 127) * 256; m0 = (i >> 7) * 64;
    }
    const int t  = threadIdx.x;
    const int w  = t >> 6, wl = t & 63, l16 = wl & 15, grp = wl >> 4;

    __shared__ __align__(16) u16 AT[2][64 * 64];
    __shared__ __align__(16) u16 BT[2][256 * 64];

    f32x4 acc[4][4];
    #pragma unroll
    for (int i = 0; i < 4; ++i)
        #pragma unroll
        for (int j = 0; j < 4; ++j) acc[i][j] = (f32x4){0.f, 0.f, 0.f, 0.f};

    GEMM_MAIN();

    #pragma unroll
    for (int mi = 0; mi < 4; ++mi)
        #pragma unroll
        for (int ni = 0; ni < 4; ++ni)
            #pragma unroll
            for (int r = 0; r < 4; ++r) {
                int m = m0 + mi*16 + grp*4 + r;
                int n = n0 + w*64 + ni*16 + l16;
                int bb = n >> lgS, s = n & ((1 << lgS) - 1);
                Yf[(((size_t)bb * 256 + m) << lgS) + s] = acc[mi][ni][r];
            }
}

// ---------------- attention: one wave per (pixel, head-pair) ----------------
// grid 8192 linear, XCD-swizzled: each XCD owns a contiguous 1024-pixel band.
__global__ __launch_bounds__(256) void k_attn(
    const u16* __restrict__ tK, const u16* __restrict__ tQ, const u16* __restrict__ tV,
    const u16* __restrict__ bK, const u16* __restrict__ bQ, const u16* __restrict__ bV,
    u16* __restrict__ tRet, u16* __restrict__ pat)
{
    const int lbid = (blockIdx.x & 7) * 1024 + (blockIdx.x >> 3);  // 8192 = 8*1024
    const int pix = lbid & 4095;    // 0..4095
    const int b   = lbid >> 12;
    const int w   = threadIdx.x >> 6;
    const int wl  = threadIdx.x & 63;
    const int l16 = wl & 15, grp = wl >> 4;
    const int y = pix >> 6, x = pix & 63;

    __shared__ u16 Ssm[4][16][24];        // [wave][q][kpos], stride 48B
    __shared__ __align__(16) u16 Vsm[4][2][16][16]; // [wave][v-half][kpos][v16]

    // position p = l16: p=0 top pixel, p=1..9 bot neighbor, p>=10 pad
    const int p = l16;
    bool pvalid = false; int bpix = 0; const bool istop = (p == 0);
    if (p == 0) pvalid = true;
    else if (p < 10) {
        int pm = p - 1; int i = (pm * 11) >> 5; int j = pm - 3 * i;
        int by = 2 * y + i - 1, bx = 2 * x + j - 1;
        pvalid = ((unsigned)by < 128u) && ((unsigned)bx < 128u);
        bpix = by * 128 + bx;
    }
    const size_t topRow = ((size_t)b * 4096  + pix)  * 256;
    const size_t botRow = ((size_t)b * 16384 + bpix) * 256;
    const float scale = 0.17677669529663687f; // 1/sqrt(32)

    #pragma unroll
    for (int hi = 0; hi < 2; ++hi) {
        const int h = w + hi * 4;
        const size_t off = (istop ? topRow : botRow) + h * 32 + grp * 8;
        bh8 aQ = {}, aK = {}, vV = {};
        if (pvalid) {
            if (istop) {
                aQ = *(const bh8*)(tQ + off);
                aK = *(const bh8*)(tK + off);
                vV = *(const bh8*)(tV + off);
            } else {
                aQ = *(const bh8*)(bQ + off);
                aK = *(const bh8*)(bK + off);
                vV = *(const bh8*)(bV + off);
            }
        }
        // stage V rows (zeros for invalid rows): half = grp>>1, chunk (grp&1)*8
        *(bh8*)&Vsm[w][grp >> 1][p][(grp & 1) * 8] = vV;

        // S = Q.K^T   (A rows = query pos, B cols = key pos, k = d contiguous)
        f32x4 z = {0.f, 0.f, 0.f, 0.f};
        f32x4 sC = __builtin_amdgcn_mfma_f32_16x16x32_bf16(aQ, aK, z, 0, 0, 0);
        #pragma unroll
        for (int r = 0; r < 4; ++r)
            Ssm[w][grp * 4 + r][l16] = f2b(sC[r] * scale);

        // A_S: row q=l16, k-slots (grp,i<4) = kpos 4*grp+i ; slots i>=4 zero
        bh8 aS = {};
        *(bh4*)&aS = *(const bh4*)&Ssm[w][l16][grp * 4];

        // B_V: slot (grp,i<4) = V[kpos=4*grp+i][v], consistent with A_S labeling
        bh8 bv0 = {}, bv1 = {};
        #pragma unroll
        for (int j = 0; j < 4; ++j) {
            bv0[j] = (short)Vsm[w][0][grp * 4 + j][l16];
            bv1[j] = (short)Vsm[w][1][grp * 4 + j][l16];
        }
        f32x4 oc0 = __builtin_amdgcn_mfma_f32_16x16x32_bf16(aS, bv0, z, 0, 0, 0);
        f32x4 oc1 = __builtin_amdgcn_mfma_f32_16x16x32_bf16(aS, bv1, z, 0, 0, 0);

        // outputs: row q = grp*4+r, col v = l16 (+16 for oc1)
        if (grp == 0) {
            size_t o = topRow + (size_t)h * 32;
            tRet[o + l16]      = f2b(oc0[0]);
            tRet[o + 16 + l16] = f2b(oc1[0]);
        }
        #pragma unroll
        for (int r = 0; r < 4; ++r) {
            int q = grp * 4 + r;
            if (q >= 1 && q <= 9) {
                size_t base = ((((size_t)b * 8 + h) * 9 + (q - 1)) * 4096 + pix) * 32;
                pat[base + l16]      = f2b(oc0[r]);
                pat[base + 16 + l16] = f2b(oc1[r]);
            }
        }
    }
}

// ---------------- fold: pat [b][h][9][4096][32] -> botRet (B,16384,256) bf16 ----------------
// grid 4096, XCD-swizzled: contiguous bpix bands per XCD for pat-line reuse.
__global__ __launch_bounds__(256) void k_fold(
    const u16* __restrict__ pat, u16* __restrict__ botRet)
{
    const int lbid = (blockIdx.x & 7) * 512 + (blockIdx.x >> 3);   // 4096 = 8*512
    int tid = lbid * 256 + threadIdx.x;             // 1,048,576 threads
    int vchunk = tid & 3;                           // 8 v's each
    int ri = tid >> 2;                              // (b*16384 + bpix)*8 + h
    int b = ri >> 17;
    int bpix = (ri >> 3) & 16383;
    int h = ri & 7;
    int by = bpix >> 7, bx = bpix & 127;
    int v0 = vchunk * 8;

    float acc[8];
    #pragma unroll
    for (int e = 0; e < 8; ++e) acc[e] = 0.f;

    for (int iy = 0; iy < 3; ++iy) {
        int ty = by + 1 - iy;
        if (ty & 1) continue;
        int yy = ty >> 1;
        if ((unsigned)yy >= 64u) continue;
        for (int jx = 0; jx < 3; ++jx) {
            int tx = bx + 1 - jx;
            if (tx & 1) continue;
            int xx = tx >> 1;
            if ((unsigned)xx >= 64u) continue;
            int q = iy * 3 + jx;
            size_t addr = ((((size_t)b * 8 + h) * 9 + q) * 4096 + (yy * 64 + xx)) * 32 + v0;
            uint4 pv = *(const uint4*)&pat[addr];
            const u16* pp = (const u16*)&pv;
            #pragma unroll
            for (int e = 0; e < 8; ++e) acc[e] += b2f(pp[e]);
        }
    }
    u16 tmp[8];
    #pragma unroll
    for (int e = 0; e < 8; ++e) tmp[e] = f2b(acc[e]);
    *(uint4*)&botRet[((size_t)b * 16384 + bpix) * 256 + h * 32 + v0] = *(uint4*)tmp;
}

extern "C" void kernel_launch(void* const* d_in, const int* in_sizes, int n_in,
                              void* d_out, int out_size, void* d_ws, size_t ws_size,
                              hipStream_t stream) {
    const float* top_feat = (const float*)d_in[0];
    const float* bot_feat = (const float*)d_in[1];

    float* out     = (float*)d_out;
    float* top_out = out;                            // (2,256,64,64)
    float* bot_out = out + (size_t)2 * 256 * 4096;   // (2,256,128,128)

    const size_t TOPU = (size_t)2 * 4096  * 256;   // ushort counts
    const size_t BOTU = (size_t)2 * 16384 * 256;
    char* p = (char*)d_ws;
    u16* Wb     = (u16*)p;  p += (size_t)8 * 65536 * 2;   // 1.0 MB
    u16* tK     = (u16*)p;  p += TOPU * 2;
    u16* tQ     = (u16*)p;  p += TOPU * 2;
    u16* tV     = (u16*)p;  p += TOPU * 2;                // 12.6 MB
    u16* bK     = (u16*)p;  p += BOTU * 2;
    u16* bQ     = (u16*)p;  p += BOTU * 2;
    u16* bV     = (u16*)p;  p += BOTU * 2;                // 50.3 MB
    u16* tRet   = (u16*)p;  p += TOPU * 2;                // 4.2 MB
    u16* pat    = (u16*)p;  p += (size_t)2*8*9*4096*32*2; // 37.7 MB
    u16* botRet = (u16*)p;  p += BOTU * 2;                // 16.8 MB

    // weights -> bf16 (order: tK,tQ,tV,bK,bQ,bV,tFuse,bFuse)
    k_cvt_w<<<dim3(64, 8), dim3(256), 0, stream>>>(
        (const float*)d_in[2], (const float*)d_in[3], (const float*)d_in[4],
        (const float*)d_in[5], (const float*)d_in[6], (const float*)d_in[7],
        (const float*)d_in[8], (const float*)d_in[9], Wb);

    // fused QKV projections: stage-A-once + zero-sync main loop, XCD-swizzled
    k_proj<<<dim3(960), dim3(512), 0, stream>>>(top_feat, bot_feat, Wb,
                                                tK, bK, TOPU, BOTU);

    // attention (XCD-swizzled pixel bands)
    k_attn<<<dim3(8192), dim3(256), 0, stream>>>(tK, tQ, tV, bK, bQ, bV, tRet, pat);

    // fold bot windows (XCD-swizzled)
    k_fold<<<dim3(4096), dim3(256), 0, stream>>>(pat, botRet);

    // fuse GEMMs, top+bot merged -> fp32 channel-major outputs
    k_fuse<<<dim3(640), dim3(256), 0, stream>>>(Wb, tRet, botRet, top_out, bot_out);
}

// Round 18
// 87.476 us; speedup vs baseline: 1.2699x; 1.1799x over previous
//
#include <hip/hip_runtime.h>
#include <hip/hip_bf16.h>
#include <math.h>

// PLANAttention, bf16/MFMA pipeline (FINAL = round 11/15 verified best, 88.1us:
// nine k_proj structural variants explored rounds 6-17; this is the plateau.
// attn/fold/fuse are at their HBM traffic floors):
//  1) k_cvt_w: 8 weight mats fp32 -> bf16 (Wb)
//  2) k_proj: fused QKV proj (top+bot merged) -> pixel-major bf16 K/Q/V
//  3) k_attn: per (pixel,head) wave: S=Q.K^T (1 mfma), O=S.V (2 mfma)
//  4) k_fold: pat -> botRet bf16 (gather <=4 windows, no atomics)
//  5) k_fuse: fuse-top + fuse-bot merged -> fp32 d_out

typedef __attribute__((ext_vector_type(8))) short  bh8;
typedef __attribute__((ext_vector_type(4))) short  bh4;
typedef __attribute__((ext_vector_type(4))) float  f32x4;
typedef unsigned short u16;

static __device__ __forceinline__ u16 f2b(float x) {
    __hip_bfloat16 h = __float2bfloat16(x);
    return __builtin_bit_cast(u16, h);
}
static __device__ __forceinline__ float b2f(u16 u) {
    unsigned v = ((unsigned)u) << 16;
    return __builtin_bit_cast(float, v);
}

// async global->LDS, 16B per lane. Dest must be linear in lane (wave-uniform base + lane*16).
static __device__ __forceinline__ void gload16(const u16* g, u16* l) {
    __builtin_amdgcn_global_load_lds(
        (const __attribute__((address_space(1))) unsigned int*)g,
        (__attribute__((address_space(3))) unsigned int*)l, 16, 0, 0);
}

// ---------------- weight convert: 8 x 256x256 fp32 -> bf16 ----------------
__global__ __launch_bounds__(256) void k_cvt_w(
    const float* w0, const float* w1, const float* w2, const float* w3,
    const float* w4, const float* w5, const float* w6, const float* w7,
    u16* __restrict__ Wb)
{
    const float* srcs[8] = {w0,w1,w2,w3,w4,w5,w6,w7};
    const float* src = srcs[blockIdx.y];
    int i = (blockIdx.x * 256 + threadIdx.x) * 4;
    float4 v = *(const float4*)&src[i];
    u16 tmp[4] = { f2b(v.x), f2b(v.y), f2b(v.z), f2b(v.w) };
    *(uint2*)&Wb[(size_t)blockIdx.y * 65536 + i] = *(uint2*)tmp;
}

// ---------------- proj (top + bot merged), BM=128, BK=32, 512 threads ----------------
// grid 960 linear, XCD-swizzled: lbid = (bid%8)*120 + bid/8 -> each XCD gets
// 40 consecutive y-tiles x all 3 n-tiles (A-tile triple shares one L2).
// y<64 top, else bot. BM=128, BN=256, BK=32 (8 K-steps), 8 waves (2M x 4N).
// A[m=pix][k=c]: thread t -> apix = t&127, oct = t>>7; 8 coalesced dword rows
// -> named regs -> cvt -> ds_write_b128 at slot = oct ^ ((apix>>1)&3).
// B[n=o][k=c]: gload16, source chunk cs = c ^ ((row>>1)&3), linear dest.
__global__ __launch_bounds__(512) void k_proj(
    const float* __restrict__ top_feat, const float* __restrict__ bot_feat,
    const u16* __restrict__ Wb,
    u16* __restrict__ tK, u16* __restrict__ bK, size_t TOPU, size_t BOTU)
{
    const int lbid  = (blockIdx.x & 7) * 120 + (blockIdx.x >> 3);  // bijective, 960=8*120
    const int yb    = lbid / 3;
    const int n0    = (lbid - yb * 3) * 256;
    const bool istop = yb < 64;
    const float* feat = istop ? top_feat : bot_feat;
    const u16* Bw   = istop ? Wb : (Wb + 3 * 65536);
    u16* Yp         = istop ? tK : bK;
    const size_t arrsz = istop ? TOPU : BOTU;
    const int S     = istop ? 4096 : 16384;
    const int m0g   = (istop ? yb : (yb - 64)) * 128;
    const int b     = istop ? (m0g >> 12) : (m0g >> 14);
    const int pix0  = m0g & (S - 1);
    const float* Xb = feat + (size_t)b * 256 * S;
    const int t  = threadIdx.x;
    const int w  = t >> 6, wl = t & 63, l16 = wl & 15, grp = wl >> 4;
    const int wm = w >> 2, wn = w & 3;   // wave tile: M-half, N-quarter
    const int apix = t & 127;            // lane's pixel for A staging
    const int oct  = t >> 7;             // c-octet within 32-wide K-tile

    __shared__ __align__(16) u16 AT[2][128 * 32];   // 16 KB
    __shared__ __align__(16) u16 BT[2][256 * 32];   // 32 KB

    float rA[8];   // 1-deep, statically indexed only

#define PA_LOAD(kk) do {                                                      \
        _Pragma("unroll")                                                     \
        for (int e = 0; e < 8; ++e)                                           \
            rA[e] = Xb[(size_t)((kk) + oct * 8 + e) * S + pix0 + apix];       \
    } while (0)

#define PA_WRITE(bufi) do {                                                   \
        u16 tmp[8];                                                           \
        _Pragma("unroll")                                                     \
        for (int e = 0; e < 8; ++e) tmp[e] = f2b(rA[e]);                      \
        int slot = oct ^ ((apix >> 1) & 3);                                   \
        *(uint4*)&AT[bufi][apix * 32 + slot * 8] = *(uint4*)tmp;              \
    } while (0)

#define PB_STAGE(bufi, kk) do {                                               \
        _Pragma("unroll")                                                     \
        for (int it = 0; it < 2; ++it) {                                      \
            int lin = it * 512 + t;                                           \
            int row = lin >> 2, c = lin & 3;                                  \
            int cs = c ^ ((row >> 1) & 3);                                    \
            gload16(&Bw[(size_t)(n0 + row) * 256 + (kk) + cs * 8],            \
                    &BT[bufi][lin * 8]);                                      \
        }                                                                     \
    } while (0)

    f32x4 acc[4][4];
    #pragma unroll
    for (int i = 0; i < 4; ++i)
        #pragma unroll
        for (int j = 0; j < 4; ++j) acc[i][j] = (f32x4){0.f, 0.f, 0.f, 0.f};

    PA_LOAD(0);
    PB_STAGE(0, 0);
    PA_WRITE(0);
    int cur = 0;
    for (int kt = 0; kt < 8; ++kt) {
        __syncthreads();   // buf[cur] staged; prev reads done
        if (kt < 7) {
            PA_LOAD((kt + 1) * 32);          // issue early (hides under MFMA)
            PB_STAGE(cur ^ 1, (kt + 1) * 32);
        }
        bh8 af[4], bf[4];
        #pragma unroll
        for (int mi = 0; mi < 4; ++mi) {
            int row = wm * 64 + mi * 16 + l16;
            int slot = grp ^ ((row >> 1) & 3);
            af[mi] = *(const bh8*)&AT[cur][row * 32 + slot * 8];
        }
        #pragma unroll
        for (int ni = 0; ni < 4; ++ni) {
            int row = wn * 64 + ni * 16 + l16;
            int slot = grp ^ ((row >> 1) & 3);
            bf[ni] = *(const bh8*)&BT[cur][row * 32 + slot * 8];
        }
        #pragma unroll
        for (int mi = 0; mi < 4; ++mi)
            #pragma unroll
            for (int ni = 0; ni < 4; ++ni)
                acc[mi][ni] = __builtin_amdgcn_mfma_f32_16x16x32_bf16(
                    af[mi], bf[ni], acc[mi][ni], 0, 0, 0);
        if (kt < 7) PA_WRITE(cur ^ 1);       // cvt+write late (loads landed)
        cur ^= 1;
    }
#undef PA_LOAD
#undef PA_WRITE
#undef PB_STAGE

    #pragma unroll
    for (int mi = 0; mi < 4; ++mi)
        #pragma unroll
        for (int ni = 0; ni < 4; ++ni)
            #pragma unroll
            for (int r = 0; r < 4; ++r) {
                int m = m0g + wm*64 + mi*16 + grp*4 + r;
                int n = n0 + wn*64 + ni*16 + l16;
                Yp[(size_t)(n >> 8) * arrsz + (size_t)m * 256 + (n & 255)]
                    = f2b(acc[mi][ni][r]);
            }
}

// Shared GEMM staging/compute for k_fuse (round-3 verified): C[m][n]=sum_k A[m][k]*B[n][k].
#define GEMM_STAGE(bufi, kk) do {                                             \
        _Pragma("unroll")                                                     \
        for (int it = 0; it < 2; ++it) {                                      \
            int lin = it * 256 + t;                                           \
            int row = lin >> 3, c = lin & 7;                                  \
            int cs = c ^ (row & 7);                                           \
            gload16(&A[(size_t)(m0 + row) * 256 + (kk) + cs * 8],             \
                    &AT[bufi][lin * 8]);                                      \
        }                                                                     \
        _Pragma("unroll")                                                     \
        for (int it = 0; it < 8; ++it) {                                      \
            int lin = it * 256 + t;                                           \
            int row = lin >> 3, c = lin & 7;                                  \
            int cs = c ^ (row & 7);                                           \
            gload16(&B[(size_t)(n0 + row) * 256 + (kk) + cs * 8],             \
                    &BT[bufi][lin * 8]);                                      \
        }                                                                     \
    } while (0)

#define GEMM_MAIN()                                                           \
    GEMM_STAGE(0, 0);                                                         \
    int cur = 0;                                                              \
    for (int kt = 0; kt < 4; ++kt) {                                          \
        __syncthreads();                                                      \
        if (kt < 3) GEMM_STAGE(cur ^ 1, (kt + 1) * 64);                       \
        _Pragma("unroll")                                                     \
        for (int ks = 0; ks < 2; ++ks) {                                      \
            bh8 af[4], bf[4];                                                 \
            _Pragma("unroll")                                                 \
            for (int mi = 0; mi < 4; ++mi) {                                  \
                int row = mi * 16 + l16;                                      \
                int pc = (ks * 4 + grp) ^ (row & 7);                          \
                af[mi] = *(const bh8*)&AT[cur][row * 64 + pc * 8];            \
            }                                                                 \
            _Pragma("unroll")                                                 \
            for (int ni = 0; ni < 4; ++ni) {                                  \
                int row = w * 64 + ni * 16 + l16;                             \
                int pc = (ks * 4 + grp) ^ (row & 7);                          \
                bf[ni] = *(const bh8*)&BT[cur][row * 64 + pc * 8];            \
            }                                                                 \
            _Pragma("unroll")                                                 \
            for (int mi = 0; mi < 4; ++mi)                                    \
                _Pragma("unroll")                                             \
                for (int ni = 0; ni < 4; ++ni)                                \
                    acc[mi][ni] = __builtin_amdgcn_mfma_f32_16x16x32_bf16(    \
                        af[mi], bf[ni], acc[mi][ni], 0, 0, 0);                \
        }                                                                     \
        cur ^= 1;                                                             \
    }

// ---------------- fuse (top + bot merged): C[m=o][n=pixrow] -> fp32 ----------------
// blocks [0,128): top (lgS=12, n-tiles 32, m-tiles 4); [128,640): bot (lgS=14, 128x4)
// B-tile sharers are bid strides 32 / 128 (== 0 mod 8) -> already same-XCD.
__global__ __launch_bounds__(256) void k_fuse(
    const u16* __restrict__ Wb, const u16* __restrict__ tRet,
    const u16* __restrict__ botRet, float* __restrict__ top_out,
    float* __restrict__ bot_out)
{
    const int bid = blockIdx.x;
    const u16* A; const u16* B; float* Yf; int lgS, n0, m0;
    if (bid < 128) {
        A = Wb + 6 * 65536; B = tRet; Yf = top_out; lgS = 12;
        n0 = (bid & 31) * 256; m0 = (bid >> 5) * 64;
    } else {
        int i = bid - 128;
        A = Wb + 7 * 65536; B = botRet; Yf = bot_out; lgS = 14;
        n0 = (i & 127) * 256; m0 = (i >> 7) * 64;
    }
    const int t  = threadIdx.x;
    const int w  = t >> 6, wl = t & 63, l16 = wl & 15, grp = wl >> 4;

    __shared__ __align__(16) u16 AT[2][64 * 64];
    __shared__ __align__(16) u16 BT[2][256 * 64];

    f32x4 acc[4][4];
    #pragma unroll
    for (int i = 0; i < 4; ++i)
        #pragma unroll
        for (int j = 0; j < 4; ++j) acc[i][j] = (f32x4){0.f, 0.f, 0.f, 0.f};

    GEMM_MAIN();

    #pragma unroll
    for (int mi = 0; mi < 4; ++mi)
        #pragma unroll
        for (int ni = 0; ni < 4; ++ni)
            #pragma unroll
            for (int r = 0; r < 4; ++r) {
                int m = m0 + mi*16 + grp*4 + r;
                int n = n0 + w*64 + ni*16 + l16;
                int bb = n >> lgS, s = n & ((1 << lgS) - 1);
                Yf[(((size_t)bb * 256 + m) << lgS) + s] = acc[mi][ni][r];
            }
}

// ---------------- attention: one wave per (pixel, head-pair) ----------------
// grid 8192 linear, XCD-swizzled: each XCD owns a contiguous 1024-pixel band
// (16 image rows) -> bot-neighbor lines (2.25x amplified) reuse one L2.
__global__ __launch_bounds__(256) void k_attn(
    const u16* __restrict__ tK, const u16* __restrict__ tQ, const u16* __restrict__ tV,
    const u16* __restrict__ bK, const u16* __restrict__ bQ, const u16* __restrict__ bV,
    u16* __restrict__ tRet, u16* __restrict__ pat)
{
    const int lbid = (blockIdx.x & 7) * 1024 + (blockIdx.x >> 3);  // 8192 = 8*1024
    const int pix = lbid & 4095;    // 0..4095
    const int b   = lbid >> 12;
    const int w   = threadIdx.x >> 6;
    const int wl  = threadIdx.x & 63;
    const int l16 = wl & 15, grp = wl >> 4;
    const int y = pix >> 6, x = pix & 63;

    __shared__ u16 Ssm[4][16][24];        // [wave][q][kpos], stride 48B
    __shared__ __align__(16) u16 Vsm[4][2][16][16]; // [wave][v-half][kpos][v16]

    // position p = l16: p=0 top pixel, p=1..9 bot neighbor, p>=10 pad
    const int p = l16;
    bool pvalid = false; int bpix = 0; const bool istop = (p == 0);
    if (p == 0) pvalid = true;
    else if (p < 10) {
        int pm = p - 1; int i = (pm * 11) >> 5; int j = pm - 3 * i;
        int by = 2 * y + i - 1, bx = 2 * x + j - 1;
        pvalid = ((unsigned)by < 128u) && ((unsigned)bx < 128u);
        bpix = by * 128 + bx;
    }
    const size_t topRow = ((size_t)b * 4096  + pix)  * 256;
    const size_t botRow = ((size_t)b * 16384 + bpix) * 256;
    const float scale = 0.17677669529663687f; // 1/sqrt(32)

    #pragma unroll
    for (int hi = 0; hi < 2; ++hi) {
        const int h = w + hi * 4;
        const size_t off = (istop ? topRow : botRow) + h * 32 + grp * 8;
        bh8 aQ = {}, aK = {}, vV = {};
        if (pvalid) {
            if (istop) {
                aQ = *(const bh8*)(tQ + off);
                aK = *(const bh8*)(tK + off);
                vV = *(const bh8*)(tV + off);
            } else {
                aQ = *(const bh8*)(bQ + off);
                aK = *(const bh8*)(bK + off);
                vV = *(const bh8*)(bV + off);
            }
        }
        // stage V rows (zeros for invalid rows): half = grp>>1, chunk (grp&1)*8
        *(bh8*)&Vsm[w][grp >> 1][p][(grp & 1) * 8] = vV;

        // S = Q.K^T   (A rows = query pos, B cols = key pos, k = d contiguous)
        f32x4 z = {0.f, 0.f, 0.f, 0.f};
        f32x4 sC = __builtin_amdgcn_mfma_f32_16x16x32_bf16(aQ, aK, z, 0, 0, 0);
        #pragma unroll
        for (int r = 0; r < 4; ++r)
            Ssm[w][grp * 4 + r][l16] = f2b(sC[r] * scale);

        // A_S: row q=l16, k-slots (grp,i<4) = kpos 4*grp+i ; slots i>=4 zero
        bh8 aS = {};
        *(bh4*)&aS = *(const bh4*)&Ssm[w][l16][grp * 4];

        // B_V: slot (grp,i<4) = V[kpos=4*grp+i][v], consistent with A_S labeling
        bh8 bv0 = {}, bv1 = {};
        #pragma unroll
        for (int j = 0; j < 4; ++j) {
            bv0[j] = (short)Vsm[w][0][grp * 4 + j][l16];
            bv1[j] = (short)Vsm[w][1][grp * 4 + j][l16];
        }
        f32x4 oc0 = __builtin_amdgcn_mfma_f32_16x16x32_bf16(aS, bv0, z, 0, 0, 0);
        f32x4 oc1 = __builtin_amdgcn_mfma_f32_16x16x32_bf16(aS, bv1, z, 0, 0, 0);

        // outputs: row q = grp*4+r, col v = l16 (+16 for oc1)
        if (grp == 0) {
            size_t o = topRow + (size_t)h * 32;
            tRet[o + l16]      = f2b(oc0[0]);
            tRet[o + 16 + l16] = f2b(oc1[0]);
        }
        #pragma unroll
        for (int r = 0; r < 4; ++r) {
            int q = grp * 4 + r;
            if (q >= 1 && q <= 9) {
                size_t base = ((((size_t)b * 8 + h) * 9 + (q - 1)) * 4096 + pix) * 32;
                pat[base + l16]      = f2b(oc0[r]);
                pat[base + 16 + l16] = f2b(oc1[r]);
            }
        }
    }
}

// ---------------- fold: pat [b][h][9][4096][32] -> botRet (B,16384,256) bf16 ----------------
// grid 4096, XCD-swizzled: contiguous bpix bands per XCD for pat-line reuse.
__global__ __launch_bounds__(256) void k_fold(
    const u16* __restrict__ pat, u16* __restrict__ botRet)
{
    const int lbid = (blockIdx.x & 7) * 512 + (blockIdx.x >> 3);   // 4096 = 8*512
    int tid = lbid * 256 + threadIdx.x;             // 1,048,576 threads
    int vchunk = tid & 3;                           // 8 v's each
    int ri = tid >> 2;                              // (b*16384 + bpix)*8 + h
    int b = ri >> 17;
    int bpix = (ri >> 3) & 16383;
    int h = ri & 7;
    int by = bpix >> 7, bx = bpix & 127;
    int v0 = vchunk * 8;

    float acc[8];
    #pragma unroll
    for (int e = 0; e < 8; ++e) acc[e] = 0.f;

    for (int iy = 0; iy < 3; ++iy) {
        int ty = by + 1 - iy;
        if (ty & 1) continue;
        int yy = ty >> 1;
        if ((unsigned)yy >= 64u) continue;
        for (int jx = 0; jx < 3; ++jx) {
            int tx = bx + 1 - jx;
            if (tx & 1) continue;
            int xx = tx >> 1;
            if ((unsigned)xx >= 64u) continue;
            int q = iy * 3 + jx;
            size_t addr = ((((size_t)b * 8 + h) * 9 + q) * 4096 + (yy * 64 + xx)) * 32 + v0;
            uint4 pv = *(const uint4*)&pat[addr];
            const u16* pp = (const u16*)&pv;
            #pragma unroll
            for (int e = 0; e < 8; ++e) acc[e] += b2f(pp[e]);
        }
    }
    u16 tmp[8];
    #pragma unroll
    for (int e = 0; e < 8; ++e) tmp[e] = f2b(acc[e]);
    *(uint4*)&botRet[((size_t)b * 16384 + bpix) * 256 + h * 32 + v0] = *(uint4*)tmp;
}

extern "C" void kernel_launch(void* const* d_in, const int* in_sizes, int n_in,
                              void* d_out, int out_size, void* d_ws, size_t ws_size,
                              hipStream_t stream) {
    const float* top_feat = (const float*)d_in[0];
    const float* bot_feat = (const float*)d_in[1];

    float* out     = (float*)d_out;
    float* top_out = out;                            // (2,256,64,64)
    float* bot_out = out + (size_t)2 * 256 * 4096;   // (2,256,128,128)

    const size_t TOPU = (size_t)2 * 4096  * 256;   // ushort counts
    const size_t BOTU = (size_t)2 * 16384 * 256;
    char* p = (char*)d_ws;
    u16* Wb     = (u16*)p;  p += (size_t)8 * 65536 * 2;   // 1.0 MB
    u16* tK     = (u16*)p;  p += TOPU * 2;
    u16* tQ     = (u16*)p;  p += TOPU * 2;
    u16* tV     = (u16*)p;  p += TOPU * 2;                // 12.6 MB
    u16* bK     = (u16*)p;  p += BOTU * 2;
    u16* bQ     = (u16*)p;  p += BOTU * 2;
    u16* bV     = (u16*)p;  p += BOTU * 2;                // 50.3 MB
    u16* tRet   = (u16*)p;  p += TOPU * 2;                // 4.2 MB
    u16* pat    = (u16*)p;  p += (size_t)2*8*9*4096*32*2; // 37.7 MB
    u16* botRet = (u16*)p;  p += BOTU * 2;                // 16.8 MB

    // weights -> bf16 (order: tK,tQ,tV,bK,bQ,bV,tFuse,bFuse)
    k_cvt_w<<<dim3(64, 8), dim3(256), 0, stream>>>(
        (const float*)d_in[2], (const float*)d_in[3], (const float*)d_in[4],
        (const float*)d_in[5], (const float*)d_in[6], (const float*)d_in[7],
        (const float*)d_in[8], (const float*)d_in[9], Wb);

    // fused QKV projections, top+bot merged, BM=128 / 512 threads, XCD-swizzled
    k_proj<<<dim3(960), dim3(512), 0, stream>>>(top_feat, bot_feat, Wb,
                                                tK, bK, TOPU, BOTU);

    // attention (XCD-swizzled pixel bands)
    k_attn<<<dim3(8192), dim3(256), 0, stream>>>(tK, tQ, tV, bK, bQ, bV, tRet, pat);

    // fold bot windows (XCD-swizzled)
    k_fold<<<dim3(4096), dim3(256), 0, stream>>>(pat, botRet);

    // fuse GEMMs, top+bot merged -> fp32 channel-major outputs
    k_fuse<<<dim3(640), dim3(256), 0, stream>>>(Wb, tRet, botRet, top_out, bot_out);
}